// Round 5
// baseline (177.169 us; speedup 1.0000x reference)
//
#include <hip/hip_runtime.h>
#include <math.h>

// SpiralNet bf16-MFMA v5.
// vs R4: B-pack is staged into LDS (48 KB chunks) and read via ds_read_b128 --
// weights leave the vmem/L1/L2 path entirely, which is now dedicated to the
// random A-gathers. block=256 (4 waves, MR=2 -> 128 rows), 48KB LDS,
// __launch_bounds__(256,3) -> 3 blocks/CU resident (144KB LDS), 12 waves/CU.
// Layer1 (96KB B) stages in 2 chunks of 6 spiral-steps with barriers between.

typedef __bf16 bf16;
typedef bf16  bf16x4 __attribute__((ext_vector_type(4)));
typedef bf16  bf16x8 __attribute__((ext_vector_type(8)));
typedef float f32x4  __attribute__((ext_vector_type(4)));

// Pack W [K][COUT] f32 into fragment-ordered bf16:
// frag f = (s*CC + cc)*NT + t; within frag, element lane*8+j is
// W[k = s*CIN + cc*32 + (lane>>4)*8 + j][col = t*16 + (lane&15)].
template<int CIN, int COUT>
__device__ inline void pack_one(const float* __restrict__ W, bf16* __restrict__ BP, int e) {
    constexpr int NT = COUT / 16, CC = CIN / 32;
    const int f = e >> 9, r = e & 511, lane = r >> 3, j = r & 7;
    const int t = f % NT, cc = (f / NT) % CC, s = f / (NT * CC);
    const int col = t * 16 + (lane & 15);
    const int k   = s * CIN + cc * 32 + (lane >> 4) * 8 + j;
    BP[e] = (bf16)W[k * COUT + col];
}

__global__ __launch_bounds__(256)
void prep_all(const float* __restrict__ x, bf16* __restrict__ xb,
              const float* __restrict__ W0, const float* __restrict__ W1,
              const float* __restrict__ W2, bf16* __restrict__ B0,
              bf16* __restrict__ B1, bf16* __restrict__ B2, int n)
{
    const int gid = blockIdx.x * 256 + threadIdx.x;
    const int e = gid * 4;
    if (e < n * 32) {
        const f32x4 v = *reinterpret_cast<const f32x4*>(x + e);
        bf16x4 o = {(bf16)v[0], (bf16)v[1], (bf16)v[2], (bf16)v[3]};
        *reinterpret_cast<bf16x4*>(xb + e) = o;
    }
    if (gid < 384 * 64)                       pack_one<32, 64>(W0, B0, gid);
    else if (gid < 384 * 64 + 768 * 64)       pack_one<64, 64>(W1, B1, gid - 384 * 64);
    else if (gid < 384 * 64 + 768 * 64 + 768 * 32)
                                              pack_one<64, 32>(W2, B2, gid - 384 * 64 - 768 * 64);
}

template<int CIN, int COUT, bool ELU, typename TOUT>
__global__ __launch_bounds__(256, 3)
void spiral_mfma(const bf16* __restrict__ h, const int* __restrict__ idx,
                 const bf16* __restrict__ BP, const float* __restrict__ bias,
                 TOUT* __restrict__ out, int n)
{
    constexpr int CC = CIN / 32;            // 32-k chunks per spiral step
    constexpr int NT = COUT / 16;           // 16-col output tiles
    constexpr int PS = CIN * COUT;          // B elems per spiral step
    constexpr int SC = (24576 / PS < 12) ? (24576 / PS) : 12;  // steps per 48KB chunk
    constexpr int NCH = 12 / SC;            // chunks (1 for L0/L2, 2 for L1)

    __shared__ bf16 Bs[SC * PS];            // 48 KB

    const int tid  = threadIdx.x;
    const int lane = tid & 63;
    const int wave = tid >> 6;
    const int m    = lane & 15;
    const int quad = lane >> 4;
    const int i0   = (blockIdx.x * 4 + wave) * 32;   // MR=2 tiles of 16 rows
    const bool valid = (i0 < n);                      // n%32==0: all-or-none per wave

    // Prefetch both tiles' gather indices (48B/row, 16B-aligned).
    int rg0[12], rg1[12];
    if (valid) {
        const int4* p0 = reinterpret_cast<const int4*>(idx + (size_t)(i0 + m) * 12);
        const int4* p1 = reinterpret_cast<const int4*>(idx + (size_t)(i0 + 16 + m) * 12);
        const int4 q00 = p0[0], q01 = p0[1], q02 = p0[2];
        const int4 q10 = p1[0], q11 = p1[1], q12 = p1[2];
        rg0[0]=q00.x; rg0[1]=q00.y; rg0[2]=q00.z; rg0[3]=q00.w;
        rg0[4]=q01.x; rg0[5]=q01.y; rg0[6]=q01.z; rg0[7]=q01.w;
        rg0[8]=q02.x; rg0[9]=q02.y; rg0[10]=q02.z; rg0[11]=q02.w;
        rg1[0]=q10.x; rg1[1]=q10.y; rg1[2]=q10.z; rg1[3]=q10.w;
        rg1[4]=q11.x; rg1[5]=q11.y; rg1[6]=q11.z; rg1[7]=q11.w;
        rg1[8]=q12.x; rg1[9]=q12.y; rg1[10]=q12.z; rg1[11]=q12.w;
    }

    f32x4 acc0[NT] = {}, acc1[NT] = {};

    #pragma unroll
    for (int c = 0; c < NCH; ++c) {
        if (c) __syncthreads();             // Bs reuse: wait for consumers
        // Stage chunk c of B-pack into LDS (contiguous copy, 16B per thread/round).
        const bf16* src = BP + (size_t)c * SC * PS;
        #pragma unroll
        for (int r2 = tid; r2 < SC * PS / 8; r2 += 256)
            *reinterpret_cast<bf16x8*>(&Bs[r2 * 8]) =
                *reinterpret_cast<const bf16x8*>(&src[r2 * 8]);
        __syncthreads();

        if (valid) {
            #pragma unroll
            for (int sl = 0; sl < SC; ++sl) {
                const int s = c * SC + sl;
                #pragma unroll
                for (int cc = 0; cc < CC; ++cc) {
                    const int co = cc * 32 + quad * 8;
                    const bf16x8 a0 = *reinterpret_cast<const bf16x8*>(
                        h + (size_t)rg0[s] * CIN + co);
                    const bf16x8 a1 = *reinterpret_cast<const bf16x8*>(
                        h + (size_t)rg1[s] * CIN + co);
                    #pragma unroll
                    for (int t = 0; t < NT; ++t) {
                        const bf16x8 b = *reinterpret_cast<const bf16x8*>(
                            &Bs[((sl * CC + cc) * NT + t) * 512 + lane * 8]);
                        acc0[t] = __builtin_amdgcn_mfma_f32_16x16x32_bf16(a0, b, acc0[t], 0, 0, 0);
                        acc1[t] = __builtin_amdgcn_mfma_f32_16x16x32_bf16(a1, b, acc1[t], 0, 0, 0);
                    }
                }
            }
        }
    }

    if (!valid) return;

    // Epilogue: D[row = quad*4+g][col = t*16+m]; n%32==0 -> no row guards.
    #pragma unroll
    for (int t = 0; t < NT; ++t) {
        const int col = t * 16 + m;
        const float bv = bias[col];
        #pragma unroll
        for (int g = 0; g < 4; ++g) {
            {
                const int row = i0 + quad * 4 + g;
                float v = acc0[t][g] + bv;
                if (ELU) v = (v > 0.f) ? v : (__expf(v) - 1.f);
                out[(size_t)row * COUT + col] = (TOUT)v;
            }
            {
                const int row = i0 + 16 + quad * 4 + g;
                float v = acc1[t][g] + bv;
                if (ELU) v = (v > 0.f) ? v : (__expf(v) - 1.f);
                out[(size_t)row * COUT + col] = (TOUT)v;
            }
        }
    }
}

extern "C" void kernel_launch(void* const* d_in, const int* in_sizes, int n_in,
                              void* d_out, int out_size, void* d_ws, size_t ws_size,
                              hipStream_t stream) {
    const float* x   = (const float*)d_in[0];   // [N,32] fp32
    const int*   idx = (const int*)d_in[1];     // [N,12]
    const float* W0  = (const float*)d_in[2];   // [384,64]
    const float* b0  = (const float*)d_in[3];
    const float* W1  = (const float*)d_in[4];   // [768,64]
    const float* b1  = (const float*)d_in[5];
    const float* W2  = (const float*)d_in[6];   // [768,32]
    const float* b2  = (const float*)d_in[7];
    float* out = (float*)d_out;                 // [N,32] fp32

    const int n = in_sizes[0] / 32;             // N = 100000

    bf16* xb = (bf16*)d_ws;                     // [n,32]
    bf16* h1 = xb + (size_t)n * 32;             // [n,64]
    bf16* h2 = h1 + (size_t)n * 64;             // [n,64]
    bf16* B0 = h2 + (size_t)n * 64;             // 384*64  (48 KB)
    bf16* B1 = B0 + 384 * 64;                   // 768*64  (96 KB)
    bf16* B2 = B1 + 768 * 64;                   // 768*32  (48 KB)

    dim3 blk(256);
    const int prep_threads = n * 8;             // covers n*32/4 cvt + 98304 pack
    prep_all<<<(prep_threads + 255) / 256, blk, 0, stream>>>(x, xb, W0, W1, W2, B0, B1, B2, n);

    const int grid = (n + 127) / 128;           // 4 waves x 32 rows per block
    spiral_mfma<32, 64, true,  bf16 ><<<grid, blk, 0, stream>>>(xb, idx, B0, b0, h1,  n);
    spiral_mfma<64, 64, true,  bf16 ><<<grid, blk, 0, stream>>>(h1, idx, B1, b1, h2,  n);
    spiral_mfma<64, 32, false, float><<<grid, blk, 0, stream>>>(h2, idx, B2, b2, out, n);
}